// Round 8
// baseline (655.733 us; speedup 1.0000x reference)
//
#include <hip/hip_runtime.h>
#include <hip/hip_bf16.h>

// Nav_64939905516231 (VIN value iteration), MI355X gfx950.
// B=64,H=W=64,dim_h=150,n_hat=8,n_act=4,K=10. fp32 in/out, maze int32.
// Collapses: r = conv5x5(m,W_eff)+b_eff (150ch folded); q_t = q0 + conv5x5(v,w).
// 2 kernels: A = prep+r+q0; B = 10 fused steps + projection, redundant halo
// compute (block owns 16 rows, computes shrinking region).
// Spill ladder: R4 1024-thr vp[40]+acc[32] @VGPR64 -> 2.1GB spill, 632us.
// R5 256-thr 4px/lane @128 -> 0.6GB, 247us. R6 vp[25] patch -> 130MB, 66us.
// R7 LDS-direct taps, live ~25 floats -> no spill, 56us but VALUBusy 28%
// (2 waves/SIMD, latency-bound). R8: 1024-thr / 16 waves / 4 per SIMD,
// __launch_bounds__(1024,4); same work, 2x latency hiding.

#define NHAT 8
#define DIMH 150
#define OWN 16

typedef float v2f __attribute__((ext_vector_type(2)));

// =============== Kernel A: prep + r + q0 =================
__global__ __launch_bounds__(256) void rq_kernel(
    const int* __restrict__ maze, const float* __restrict__ emb,
    const float* __restrict__ encode_w, const float* __restrict__ encode_b,
    const float* __restrict__ r_w, const float* __restrict__ q_w,
    float* __restrict__ q0g) {
  __shared__ float wpart[250];     // 5 chunks x 50 (i,k)
  __shared__ float bpart[152];
  __shared__ float weff[2][25];
  __shared__ float bsh;
  __shared__ float Ts[4][25];
  __shared__ v2f qw2[25][4];
  __shared__ unsigned char mzt[24][68];
  __shared__ float rt[20][68];

  int tid = threadIdx.x;
  int b = blockIdx.y, A0 = blockIdx.x * OWN;

  for (int i = tid; i < 24 * 68; i += 256) {
    int mr = i / 68, mc = i % 68;
    int gy = A0 - 4 + mr, gx = mc - 2;
    unsigned char v = 3;
    if (gy >= 0 && gy < 64 && gx >= 0 && gx < 64)
      v = (unsigned char)maze[(b * 64 + gy) * 64 + gx];
    mzt[mr][mc] = v;
  }
  if (tid < 100) {
    int k = tid >> 2, j = tid & 3;
    qw2[k][j] = (v2f){q_w[(2 * j) * 25 + k], q_w[(2 * j + 1) * 25 + k]};
  }
  if (tid < 250) {
    int ik = tid % 50, chunk = tid / 50;
    int i = ik / 25, k = ik % 25;
    int c0 = chunk * 30;
    float s = 0.f;
    for (int c = c0; c < c0 + 30; ++c)
      s += r_w[c] * encode_w[c * 50 + i * 25 + k];
    wpart[tid] = s;
  }
  if (tid < 150) bpart[tid] = r_w[tid] * encode_b[tid];
  __syncthreads();
  if (tid < 50) {
    float s = 0.f;
    for (int ch = 0; ch < 5; ++ch) s += wpart[ch * 50 + tid];
    weff[tid / 25][tid % 25] = s;
  }
  if (tid == 50) {
    float s = 0.f;
    for (int c = 0; c < 150; ++c) s += bpart[c];
    bsh = s;
  }
  __syncthreads();
  if (tid < 100) {
    int val = tid / 25, k = tid % 25;
    float t = 0.f;
    if (val < 3) t = weff[0][k] * emb[val * 2] + weff[1][k] * emb[val * 2 + 1];
    Ts[val][k] = t;
  }
  __syncthreads();
  // r tile rows [A0-2, A0+18): r(A0-2+rr, cc-2) taps mzt[rr+ky][cc-2+kx]
  for (int i = tid; i < 20 * 68; i += 256) {
    int rr = i / 68, cc = i % 68;
    int gy = A0 - 2 + rr, gx = cc - 2;
    float v = 0.f;
    if (gy >= 0 && gy < 64 && gx >= 0 && gx < 64) {
      v = bsh;
#pragma unroll
      for (int ky = 0; ky < 5; ++ky)
#pragma unroll
        for (int kx = 0; kx < 5; ++kx)
          v += Ts[mzt[rr + ky][cc - 2 + kx]][ky * 5 + kx];
    }
    rt[rr][cc] = v;
  }
  __syncthreads();
  for (int i = tid; i < OWN * 64; i += 256) {
    int ly = i >> 6, gx = i & 63;
    int gy = A0 + ly;
    v2f acc[4];
#pragma unroll
    for (int j = 0; j < 4; ++j) acc[j] = (v2f){0.f, 0.f};
#pragma unroll
    for (int ky = 0; ky < 5; ++ky)
#pragma unroll
      for (int kx = 0; kx < 5; ++kx) {
        int k = ky * 5 + kx;
        float vv = rt[ly + ky][gx + kx];
        v2f vv2 = (v2f){vv, vv};
#pragma unroll
        for (int j = 0; j < 4; ++j) acc[j] += qw2[k][j] * vv2;
      }
    float* dst = q0g + ((size_t)(b * 4096 + gy * 64 + gx)) * NHAT;
    ((float4*)dst)[0] = make_float4(acc[0].x, acc[0].y, acc[1].x, acc[1].y);
    ((float4*)dst)[1] = make_float4(acc[2].x, acc[2].y, acc[3].x, acc[3].y);
  }
}

// =============== Kernel B: 10 fused VI steps + projection =================
// Block (1024 thr = 16 waves, 4/SIMD) owns rows [a0, a0+16) of image b.
// Wave = one 64-px row; lane = one pixel. v_t computed on the shrinking
// region [max(0,a0-2(10-t)), min(64, a0+16+2(10-t))) in LDS; q0 from global
// (L2-resident). Taps read straight from LDS in the FMA loop (live ~25 fl).
__global__ __launch_bounds__(1024, 4) void vi_kernel(
    const float* __restrict__ q0g, const float* __restrict__ w,
    const float* __restrict__ fc_w, float* __restrict__ out) {
  __shared__ float vbuf[2][64][68];  // lds_row = gy - a0 + 22, col = gx + 2
  __shared__ v2f wl2[25][4];
  __shared__ float fcs[4][NHAT];

  int tid = threadIdx.x;
  int b = blockIdx.y, a0 = blockIdx.x * OWN;
  int wave = tid >> 6, gx = tid & 63;

  if (tid < 100) {
    int k = tid >> 2, j = tid & 3;
    wl2[k][j] = (v2f){w[(2 * j) * 25 + k], w[(2 * j + 1) * 25 + k]};
  } else if (tid >= 128 && tid < 160) {
    int t = tid - 128;
    fcs[t >> 3][t & 7] = fc_w[t];
  }
  for (int i = tid; i < 2 * 64 * 68; i += 1024) ((float*)vbuf)[i] = 0.f;
  __syncthreads();

  const float* q0b = q0g + (size_t)b * 4096 * NHAT;
  int cur = 0;

  // v0 = max_c q0 on [a0-20, a0+36) clipped
  {
    int s = max(0, a0 - 20), e = min(64, a0 + OWN + 20);
    for (int r = s + wave; r < e; r += 16) {
      const float4* p = (const float4*)(q0b + ((size_t)r * 64 + gx) * NHAT);
      float4 f0 = p[0], f1 = p[1];
      float m = fmaxf(fmaxf(fmaxf(f0.x, f0.y), fmaxf(f0.z, f0.w)),
                      fmaxf(fmaxf(f1.x, f1.y), fmaxf(f1.z, f1.w)));
      vbuf[0][r - a0 + 22][gx + 2] = m;
    }
  }
  __syncthreads();

  for (int t = 1; t <= 10; ++t) {
    int hh = 2 * (10 - t);
    int s = max(0, a0 - hh), e = min(64, a0 + OWN + hh);
    for (int r = s + wave; r < e; r += 16) {
      int lr = r - a0 + 22;
      // issue global q0 first (latency overlap)
      const float4* p = (const float4*)(q0b + ((size_t)r * 64 + gx) * NHAT);
      float4 f0 = p[0], f1 = p[1];
      v2f a0v = (v2f){f0.x, f0.y}, a1v = (v2f){f0.z, f0.w};
      v2f a2v = (v2f){f1.x, f1.y}, a3v = (v2f){f1.z, f1.w};
      // conv taps straight from LDS (each value used exactly once)
#pragma unroll
      for (int ky = 0; ky < 5; ++ky) {
        const float* row = &vbuf[cur][lr - 2 + ky][gx];
#pragma unroll
        for (int kx = 0; kx < 5; ++kx) {
          int k = ky * 5 + kx;
          float vv = row[kx];
          v2f vv2 = (v2f){vv, vv};
          a0v += wl2[k][0] * vv2;
          a1v += wl2[k][1] * vv2;
          a2v += wl2[k][2] * vv2;
          a3v += wl2[k][3] * vv2;
        }
      }
      if (t < 10) {
        float m = fmaxf(fmaxf(fmaxf(a0v.x, a0v.y), fmaxf(a1v.x, a1v.y)),
                        fmaxf(fmaxf(a2v.x, a2v.y), fmaxf(a3v.x, a3v.y)));
        vbuf[cur ^ 1][lr][gx + 2] = m;
      } else {
        float4 o;
        float* op = &o.x;
#pragma unroll
        for (int a = 0; a < 4; ++a) {
          op[a] = fcs[a][0] * a0v.x + fcs[a][1] * a0v.y + fcs[a][2] * a1v.x +
                  fcs[a][3] * a1v.y + fcs[a][4] * a2v.x + fcs[a][5] * a2v.y +
                  fcs[a][6] * a3v.x + fcs[a][7] * a3v.y;
        }
        *(float4*)&out[((size_t)((b * 64 + r) * 64 + gx)) * 4] = o;
      }
    }
    cur ^= 1;
    if (t < 10) __syncthreads();
  }
}

extern "C" void kernel_launch(void* const* d_in, const int* in_sizes, int n_in,
                              void* d_out, int out_size, void* d_ws, size_t ws_size,
                              hipStream_t stream) {
  const int* maze = (const int*)d_in[0];
  const float* emb = (const float*)d_in[1];
  const float* encode_w = (const float*)d_in[2];
  const float* encode_b = (const float*)d_in[3];
  const float* r_w = (const float*)d_in[4];
  const float* q_w = (const float*)d_in[5];
  const float* w = (const float*)d_in[6];
  const float* fc_w = (const float*)d_in[7];
  float* out = (float*)d_out;

  float* q0 = (float*)d_ws;  // 64*64*64*8 floats = 8 MB

  dim3 grid(4, 64);  // 4 quarters x 64 images
  rq_kernel<<<grid, 256, 0, stream>>>(maze, emb, encode_w, encode_b, r_w, q_w, q0);
  vi_kernel<<<grid, 1024, 0, stream>>>(q0, w, fc_w, out);
}

// Round 9
// 131.127 us; speedup vs baseline: 5.0008x; 5.0008x over previous
//
#include <hip/hip_runtime.h>
#include <hip/hip_bf16.h>

// Nav_64939905516231 (VIN value iteration), MI355X gfx950.
// B=64,H=W=64,dim_h=150,n_hat=8,n_act=4,K=10. fp32 in/out, maze int32.
// Collapses: r = conv5x5(m,W_eff)+b_eff (150ch folded); q_t = q0 + conv5x5(v,w).
// 2 kernels: A = prep+r+q0; B = 10 fused steps + projection, redundant halo
// compute (block owns 16 rows, computes shrinking region).
// Spill ladder: R4/R8 1024-thr -> compiler forces VGPR=64 -> GBs of scratch
// spill (never use 1024-thr blocks). R7 shape (512 thr, lb(512,2), VGPR 128,
// LDS-direct taps) = no spill, 56us, VALUBusy 28% -- q0 load used BEFORE the
// conv forced vmcnt(0) ahead of the FMA chain (exposed L2 latency).
// R9: acc starts at 0; conv from LDS first; q0 added AFTER -> load latency
// hidden under ~260 cyc of FMA issue. Everything else identical to R7.

#define NHAT 8
#define DIMH 150
#define OWN 16

typedef float v2f __attribute__((ext_vector_type(2)));

// =============== Kernel A: prep + r + q0 =================
__global__ __launch_bounds__(256) void rq_kernel(
    const int* __restrict__ maze, const float* __restrict__ emb,
    const float* __restrict__ encode_w, const float* __restrict__ encode_b,
    const float* __restrict__ r_w, const float* __restrict__ q_w,
    float* __restrict__ q0g) {
  __shared__ float wpart[250];     // 5 chunks x 50 (i,k)
  __shared__ float bpart[152];
  __shared__ float weff[2][25];
  __shared__ float bsh;
  __shared__ float Ts[4][25];
  __shared__ v2f qw2[25][4];
  __shared__ unsigned char mzt[24][68];
  __shared__ float rt[20][68];

  int tid = threadIdx.x;
  int b = blockIdx.y, A0 = blockIdx.x * OWN;

  for (int i = tid; i < 24 * 68; i += 256) {
    int mr = i / 68, mc = i % 68;
    int gy = A0 - 4 + mr, gx = mc - 2;
    unsigned char v = 3;
    if (gy >= 0 && gy < 64 && gx >= 0 && gx < 64)
      v = (unsigned char)maze[(b * 64 + gy) * 64 + gx];
    mzt[mr][mc] = v;
  }
  if (tid < 100) {
    int k = tid >> 2, j = tid & 3;
    qw2[k][j] = (v2f){q_w[(2 * j) * 25 + k], q_w[(2 * j + 1) * 25 + k]};
  }
  if (tid < 250) {
    int ik = tid % 50, chunk = tid / 50;
    int i = ik / 25, k = ik % 25;
    int c0 = chunk * 30;
    float s = 0.f;
    for (int c = c0; c < c0 + 30; ++c)
      s += r_w[c] * encode_w[c * 50 + i * 25 + k];
    wpart[tid] = s;
  }
  if (tid < 150) bpart[tid] = r_w[tid] * encode_b[tid];
  __syncthreads();
  if (tid < 50) {
    float s = 0.f;
    for (int ch = 0; ch < 5; ++ch) s += wpart[ch * 50 + tid];
    weff[tid / 25][tid % 25] = s;
  }
  if (tid == 50) {
    float s = 0.f;
    for (int c = 0; c < 150; ++c) s += bpart[c];
    bsh = s;
  }
  __syncthreads();
  if (tid < 100) {
    int val = tid / 25, k = tid % 25;
    float t = 0.f;
    if (val < 3) t = weff[0][k] * emb[val * 2] + weff[1][k] * emb[val * 2 + 1];
    Ts[val][k] = t;
  }
  __syncthreads();
  // r tile rows [A0-2, A0+18): r(A0-2+rr, cc-2) taps mzt[rr+ky][cc-2+kx]
  for (int i = tid; i < 20 * 68; i += 256) {
    int rr = i / 68, cc = i % 68;
    int gy = A0 - 2 + rr, gx = cc - 2;
    float v = 0.f;
    if (gy >= 0 && gy < 64 && gx >= 0 && gx < 64) {
      v = bsh;
#pragma unroll
      for (int ky = 0; ky < 5; ++ky)
#pragma unroll
        for (int kx = 0; kx < 5; ++kx)
          v += Ts[mzt[rr + ky][cc - 2 + kx]][ky * 5 + kx];
    }
    rt[rr][cc] = v;
  }
  __syncthreads();
  for (int i = tid; i < OWN * 64; i += 256) {
    int ly = i >> 6, gx = i & 63;
    int gy = A0 + ly;
    v2f acc[4];
#pragma unroll
    for (int j = 0; j < 4; ++j) acc[j] = (v2f){0.f, 0.f};
#pragma unroll
    for (int ky = 0; ky < 5; ++ky)
#pragma unroll
      for (int kx = 0; kx < 5; ++kx) {
        int k = ky * 5 + kx;
        float vv = rt[ly + ky][gx + kx];
        v2f vv2 = (v2f){vv, vv};
#pragma unroll
        for (int j = 0; j < 4; ++j) acc[j] += qw2[k][j] * vv2;
      }
    float* dst = q0g + ((size_t)(b * 4096 + gy * 64 + gx)) * NHAT;
    ((float4*)dst)[0] = make_float4(acc[0].x, acc[0].y, acc[1].x, acc[1].y);
    ((float4*)dst)[1] = make_float4(acc[2].x, acc[2].y, acc[3].x, acc[3].y);
  }
}

// =============== Kernel B: 10 fused VI steps + projection =================
// Block (512 thr = 8 waves, 2/SIMD) owns rows [a0, a0+16) of image b.
// Wave = one 64-px row; lane = one pixel. v_t computed on the shrinking
// region [max(0,a0-2(10-t)), min(64, a0+16+2(10-t))) in LDS; q0 from global
// (L2-resident), added AFTER the conv so the vmcnt wait hides under FMA issue.
__global__ __launch_bounds__(512, 2) void vi_kernel(
    const float* __restrict__ q0g, const float* __restrict__ w,
    const float* __restrict__ fc_w, float* __restrict__ out) {
  __shared__ float vbuf[2][64][68];  // lds_row = gy - a0 + 22, col = gx + 2
  __shared__ v2f wl2[25][4];
  __shared__ float fcs[4][NHAT];

  int tid = threadIdx.x;
  int b = blockIdx.y, a0 = blockIdx.x * OWN;
  int wave = tid >> 6, gx = tid & 63;

  if (tid < 100) {
    int k = tid >> 2, j = tid & 3;
    wl2[k][j] = (v2f){w[(2 * j) * 25 + k], w[(2 * j + 1) * 25 + k]};
  } else if (tid >= 128 && tid < 160) {
    int t = tid - 128;
    fcs[t >> 3][t & 7] = fc_w[t];
  }
  for (int i = tid; i < 2 * 64 * 68; i += 512) ((float*)vbuf)[i] = 0.f;
  __syncthreads();

  const float* q0b = q0g + (size_t)b * 4096 * NHAT;
  int cur = 0;

  // v0 = max_c q0 on [a0-20, a0+36) clipped
  {
    int s = max(0, a0 - 20), e = min(64, a0 + OWN + 20);
    for (int r = s + wave; r < e; r += 8) {
      const float4* p = (const float4*)(q0b + ((size_t)r * 64 + gx) * NHAT);
      float4 f0 = p[0], f1 = p[1];
      float m = fmaxf(fmaxf(fmaxf(f0.x, f0.y), fmaxf(f0.z, f0.w)),
                      fmaxf(fmaxf(f1.x, f1.y), fmaxf(f1.z, f1.w)));
      vbuf[0][r - a0 + 22][gx + 2] = m;
    }
  }
  __syncthreads();

  for (int t = 1; t <= 10; ++t) {
    int hh = 2 * (10 - t);
    int s = max(0, a0 - hh), e = min(64, a0 + OWN + hh);
    for (int r = s + wave; r < e; r += 8) {
      int lr = r - a0 + 22;
      // issue q0 load now; first USE is after the conv loop (latency hidden)
      const float4* p = (const float4*)(q0b + ((size_t)r * 64 + gx) * NHAT);
      float4 f0 = p[0], f1 = p[1];
      v2f a0v = (v2f){0.f, 0.f}, a1v = (v2f){0.f, 0.f};
      v2f a2v = (v2f){0.f, 0.f}, a3v = (v2f){0.f, 0.f};
      // conv taps straight from LDS (each value used exactly once)
#pragma unroll
      for (int ky = 0; ky < 5; ++ky) {
        const float* row = &vbuf[cur][lr - 2 + ky][gx];
#pragma unroll
        for (int kx = 0; kx < 5; ++kx) {
          int k = ky * 5 + kx;
          float vv = row[kx];
          v2f vv2 = (v2f){vv, vv};
          a0v += wl2[k][0] * vv2;
          a1v += wl2[k][1] * vv2;
          a2v += wl2[k][2] * vv2;
          a3v += wl2[k][3] * vv2;
        }
      }
      // q0 added here -> s_waitcnt vmcnt lands after the FMA chain
      a0v += (v2f){f0.x, f0.y};
      a1v += (v2f){f0.z, f0.w};
      a2v += (v2f){f1.x, f1.y};
      a3v += (v2f){f1.z, f1.w};
      if (t < 10) {
        float m = fmaxf(fmaxf(fmaxf(a0v.x, a0v.y), fmaxf(a1v.x, a1v.y)),
                        fmaxf(fmaxf(a2v.x, a2v.y), fmaxf(a3v.x, a3v.y)));
        vbuf[cur ^ 1][lr][gx + 2] = m;
      } else {
        float4 o;
        float* op = &o.x;
#pragma unroll
        for (int a = 0; a < 4; ++a) {
          op[a] = fcs[a][0] * a0v.x + fcs[a][1] * a0v.y + fcs[a][2] * a1v.x +
                  fcs[a][3] * a1v.y + fcs[a][4] * a2v.x + fcs[a][5] * a2v.y +
                  fcs[a][6] * a3v.x + fcs[a][7] * a3v.y;
        }
        *(float4*)&out[((size_t)((b * 64 + r) * 64 + gx)) * 4] = o;
      }
    }
    cur ^= 1;
    if (t < 10) __syncthreads();
  }
}

extern "C" void kernel_launch(void* const* d_in, const int* in_sizes, int n_in,
                              void* d_out, int out_size, void* d_ws, size_t ws_size,
                              hipStream_t stream) {
  const int* maze = (const int*)d_in[0];
  const float* emb = (const float*)d_in[1];
  const float* encode_w = (const float*)d_in[2];
  const float* encode_b = (const float*)d_in[3];
  const float* r_w = (const float*)d_in[4];
  const float* q_w = (const float*)d_in[5];
  const float* w = (const float*)d_in[6];
  const float* fc_w = (const float*)d_in[7];
  float* out = (float*)d_out;

  float* q0 = (float*)d_ws;  // 64*64*64*8 floats = 8 MB

  dim3 grid(4, 64);  // 4 quarters x 64 images
  rq_kernel<<<grid, 256, 0, stream>>>(maze, emb, encode_w, encode_b, r_w, q_w, q0);
  vi_kernel<<<grid, 512, 0, stream>>>(q0, w, fc_w, out);
}

// Round 10
// 124.382 us; speedup vs baseline: 5.2719x; 1.0542x over previous
//
#include <hip/hip_runtime.h>
#include <hip/hip_bf16.h>

// Nav_64939905516231 (VIN value iteration), MI355X gfx950.
// B=64,H=W=64,dim_h=150,n_hat=8,n_act=4,K=10. fp32 in/out, maze int32.
// Collapses: r = conv5x5(m,W_eff)+b_eff (150ch folded); q_t = q0 + conv5x5(v,w).
// 2 kernels: A = prep+r+q0; B = 10 fused steps + projection, redundant halo
// compute (block owns 16 rows, computes shrinking region).
// Ladder: R4/R8 1024-thr -> compiler forces VGPR=64 -> GB-scale spills (never
// 1024 thr). R7/R9 512-thr, LDS-direct taps+weights -> no spill, ~58us,
// VALUBusy 28%: LDS pipe saturated by 100 ds_read_b64 WEIGHT re-reads per
// row-iter (compiler won't hoist 50 VGPRs of weights at its 128 budget).
// R10: weights hoisted to per-lane registers (const-indexed local array,
// fully unrolled) -> LDS issue per iter drops ~1345 -> ~145 cyc.

#define NHAT 8
#define DIMH 150
#define OWN 16

typedef float v2f __attribute__((ext_vector_type(2)));

// =============== Kernel A: prep + r + q0 =================
__global__ __launch_bounds__(256) void rq_kernel(
    const int* __restrict__ maze, const float* __restrict__ emb,
    const float* __restrict__ encode_w, const float* __restrict__ encode_b,
    const float* __restrict__ r_w, const float* __restrict__ q_w,
    float* __restrict__ q0g) {
  __shared__ float wpart[250];     // 5 chunks x 50 (i,k)
  __shared__ float bpart[152];
  __shared__ float weff[2][25];
  __shared__ float bsh;
  __shared__ float Ts[4][25];
  __shared__ v2f qw2[25][4];
  __shared__ unsigned char mzt[24][68];
  __shared__ float rt[20][68];

  int tid = threadIdx.x;
  int b = blockIdx.y, A0 = blockIdx.x * OWN;

  for (int i = tid; i < 24 * 68; i += 256) {
    int mr = i / 68, mc = i % 68;
    int gy = A0 - 4 + mr, gx = mc - 2;
    unsigned char v = 3;
    if (gy >= 0 && gy < 64 && gx >= 0 && gx < 64)
      v = (unsigned char)maze[(b * 64 + gy) * 64 + gx];
    mzt[mr][mc] = v;
  }
  if (tid < 100) {
    int k = tid >> 2, j = tid & 3;
    qw2[k][j] = (v2f){q_w[(2 * j) * 25 + k], q_w[(2 * j + 1) * 25 + k]};
  }
  if (tid < 250) {
    int ik = tid % 50, chunk = tid / 50;
    int i = ik / 25, k = ik % 25;
    int c0 = chunk * 30;
    float s = 0.f;
    for (int c = c0; c < c0 + 30; ++c)
      s += r_w[c] * encode_w[c * 50 + i * 25 + k];
    wpart[tid] = s;
  }
  if (tid < 150) bpart[tid] = r_w[tid] * encode_b[tid];
  __syncthreads();
  if (tid < 50) {
    float s = 0.f;
    for (int ch = 0; ch < 5; ++ch) s += wpart[ch * 50 + tid];
    weff[tid / 25][tid % 25] = s;
  }
  if (tid == 50) {
    float s = 0.f;
    for (int c = 0; c < 150; ++c) s += bpart[c];
    bsh = s;
  }
  __syncthreads();
  if (tid < 100) {
    int val = tid / 25, k = tid % 25;
    float t = 0.f;
    if (val < 3) t = weff[0][k] * emb[val * 2] + weff[1][k] * emb[val * 2 + 1];
    Ts[val][k] = t;
  }
  __syncthreads();
  // r tile rows [A0-2, A0+18): r(A0-2+rr, cc-2) taps mzt[rr+ky][cc-2+kx]
  for (int i = tid; i < 20 * 68; i += 256) {
    int rr = i / 68, cc = i % 68;
    int gy = A0 - 2 + rr, gx = cc - 2;
    float v = 0.f;
    if (gy >= 0 && gy < 64 && gx >= 0 && gx < 64) {
      v = bsh;
#pragma unroll
      for (int ky = 0; ky < 5; ++ky)
#pragma unroll
        for (int kx = 0; kx < 5; ++kx)
          v += Ts[mzt[rr + ky][cc - 2 + kx]][ky * 5 + kx];
    }
    rt[rr][cc] = v;
  }
  __syncthreads();
  for (int i = tid; i < OWN * 64; i += 256) {
    int ly = i >> 6, gx = i & 63;
    int gy = A0 + ly;
    v2f acc[4];
#pragma unroll
    for (int j = 0; j < 4; ++j) acc[j] = (v2f){0.f, 0.f};
#pragma unroll
    for (int ky = 0; ky < 5; ++ky)
#pragma unroll
      for (int kx = 0; kx < 5; ++kx) {
        int k = ky * 5 + kx;
        float vv = rt[ly + ky][gx + kx];
        v2f vv2 = (v2f){vv, vv};
#pragma unroll
        for (int j = 0; j < 4; ++j) acc[j] += qw2[k][j] * vv2;
      }
    float* dst = q0g + ((size_t)(b * 4096 + gy * 64 + gx)) * NHAT;
    ((float4*)dst)[0] = make_float4(acc[0].x, acc[0].y, acc[1].x, acc[1].y);
    ((float4*)dst)[1] = make_float4(acc[2].x, acc[2].y, acc[3].x, acc[3].y);
  }
}

// =============== Kernel B: 10 fused VI steps + projection =================
// Block (512 thr = 8 waves, 2/SIMD) owns rows [a0, a0+16) of image b.
// Wave = one 64-px row; lane = one pixel. v_t on the shrinking region
// [max(0,a0-2(10-t)), min(64, a0+16+2(10-t))) in LDS; q0 from global (L2).
// Conv weights live in per-lane REGISTERS (wr[4][25], const-indexed).
__global__ __launch_bounds__(512, 2) void vi_kernel(
    const float* __restrict__ q0g, const float* __restrict__ w,
    const float* __restrict__ fc_w, float* __restrict__ out) {
  __shared__ float vbuf[2][64][68];  // lds_row = gy - a0 + 22, col = gx + 2
  __shared__ v2f wl2[25][4];
  __shared__ float fcs[4][NHAT];

  int tid = threadIdx.x;
  int b = blockIdx.y, a0 = blockIdx.x * OWN;
  int wave = tid >> 6, gx = tid & 63;

  if (tid < 100) {
    int k = tid >> 2, j = tid & 3;
    wl2[k][j] = (v2f){w[(2 * j) * 25 + k], w[(2 * j + 1) * 25 + k]};
  } else if (tid >= 128 && tid < 160) {
    int t = tid - 128;
    fcs[t >> 3][t & 7] = fc_w[t];
  }
  for (int i = tid; i < 2 * 64 * 68; i += 512) ((float*)vbuf)[i] = 0.f;
  __syncthreads();

  // hoist weights LDS -> registers once (constant indices, fully unrolled)
  v2f wr[4][25];
#pragma unroll
  for (int k = 0; k < 25; ++k) {
#pragma unroll
    for (int j = 0; j < 4; ++j) wr[j][k] = wl2[k][j];
  }

  const float* q0b = q0g + (size_t)b * 4096 * NHAT;
  int cur = 0;

  // v0 = max_c q0 on [a0-20, a0+36) clipped
  {
    int s = max(0, a0 - 20), e = min(64, a0 + OWN + 20);
    for (int r = s + wave; r < e; r += 8) {
      const float4* p = (const float4*)(q0b + ((size_t)r * 64 + gx) * NHAT);
      float4 f0 = p[0], f1 = p[1];
      float m = fmaxf(fmaxf(fmaxf(f0.x, f0.y), fmaxf(f0.z, f0.w)),
                      fmaxf(fmaxf(f1.x, f1.y), fmaxf(f1.z, f1.w)));
      vbuf[0][r - a0 + 22][gx + 2] = m;
    }
  }
  __syncthreads();

  for (int t = 1; t <= 10; ++t) {
    int hh = 2 * (10 - t);
    int s = max(0, a0 - hh), e = min(64, a0 + OWN + hh);
    for (int r = s + wave; r < e; r += 8) {
      int lr = r - a0 + 22;
      // issue q0 load now; first USE after the conv loop (latency hidden)
      const float4* p = (const float4*)(q0b + ((size_t)r * 64 + gx) * NHAT);
      float4 f0 = p[0], f1 = p[1];
      v2f a0v = (v2f){0.f, 0.f}, a1v = (v2f){0.f, 0.f};
      v2f a2v = (v2f){0.f, 0.f}, a3v = (v2f){0.f, 0.f};
      // conv: taps from LDS (25 b32 reads), weights from registers
#pragma unroll
      for (int ky = 0; ky < 5; ++ky) {
        const float* row = &vbuf[cur][lr - 2 + ky][gx];
#pragma unroll
        for (int kx = 0; kx < 5; ++kx) {
          int k = ky * 5 + kx;
          float vv = row[kx];
          v2f vv2 = (v2f){vv, vv};
          a0v += wr[0][k] * vv2;
          a1v += wr[1][k] * vv2;
          a2v += wr[2][k] * vv2;
          a3v += wr[3][k] * vv2;
        }
      }
      // q0 added here -> vmcnt wait lands after the FMA chain
      a0v += (v2f){f0.x, f0.y};
      a1v += (v2f){f0.z, f0.w};
      a2v += (v2f){f1.x, f1.y};
      a3v += (v2f){f1.z, f1.w};
      if (t < 10) {
        float m = fmaxf(fmaxf(fmaxf(a0v.x, a0v.y), fmaxf(a1v.x, a1v.y)),
                        fmaxf(fmaxf(a2v.x, a2v.y), fmaxf(a3v.x, a3v.y)));
        vbuf[cur ^ 1][lr][gx + 2] = m;
      } else {
        float4 o;
        float* op = &o.x;
#pragma unroll
        for (int a = 0; a < 4; ++a) {
          op[a] = fcs[a][0] * a0v.x + fcs[a][1] * a0v.y + fcs[a][2] * a1v.x +
                  fcs[a][3] * a1v.y + fcs[a][4] * a2v.x + fcs[a][5] * a2v.y +
                  fcs[a][6] * a3v.x + fcs[a][7] * a3v.y;
        }
        *(float4*)&out[((size_t)((b * 64 + r) * 64 + gx)) * 4] = o;
      }
    }
    cur ^= 1;
    if (t < 10) __syncthreads();
  }
}

extern "C" void kernel_launch(void* const* d_in, const int* in_sizes, int n_in,
                              void* d_out, int out_size, void* d_ws, size_t ws_size,
                              hipStream_t stream) {
  const int* maze = (const int*)d_in[0];
  const float* emb = (const float*)d_in[1];
  const float* encode_w = (const float*)d_in[2];
  const float* encode_b = (const float*)d_in[3];
  const float* r_w = (const float*)d_in[4];
  const float* q_w = (const float*)d_in[5];
  const float* w = (const float*)d_in[6];
  const float* fc_w = (const float*)d_in[7];
  float* out = (float*)d_out;

  float* q0 = (float*)d_ws;  // 64*64*64*8 floats = 8 MB

  dim3 grid(4, 64);  // 4 quarters x 64 images
  rq_kernel<<<grid, 256, 0, stream>>>(maze, emb, encode_w, encode_b, r_w, q_w, q0);
  vi_kernel<<<grid, 512, 0, stream>>>(q0, w, fc_w, out);
}